// Round 12
// baseline (162.603 us; speedup 1.0000x reference)
//
#include <hip/hip_runtime.h>

// Fused UnifiedQCNNKernelClassifier, round 12: pre-duplicated weight pairs.
// R11: staging no-op (60us, VGPR 36) -> scheduler re-serializes. Counter
// arithmetic: VALU busy 5850cyc/wave ~= dense 2944 + weight-dup v_movs
// 1472-2944 + tanh 672. v_pk_fma_f32 sources are 64-bit pairs; a scalar
// SGPR weight can't feed them, so the compiler materializes (w,w) per FMA.
// Fix: prep kernel writes all weights/biases as duplicated float2 pairs into
// d_ws; dense loads them as uniform 8B values -> s_load_dwordx2 -> direct
// SGPR-pair VOP3P operand, zero movs. Math unchanged.

typedef float v2f __attribute__((ext_vector_type(2)));

constexpr int TPB = 256;

// float2-pair layout in d_ws (offsets in v2f units):
//  W1:0 b1:128 W2:144 b2:400 W3:416 b3:608 W4:620 b4:716
//  W5:724 b5:756 Wh:760 bh:776 Wf:780 bf:798  (total 800)
constexpr int OW1 = 0, OB1 = 128, OW2 = 144, OB2 = 400, OW3 = 416, OB3 = 608;
constexpr int OW4 = 620, OB4 = 716, OW5 = 724, OB5 = 756, OWH = 760, OBH = 776;
constexpr int OWF = 780, OBF = 798, NPAIR = 800;

__global__ void prep_pairs(const float* __restrict__ W1, const float* __restrict__ b1,
                           const float* __restrict__ W2, const float* __restrict__ b2,
                           const float* __restrict__ W3, const float* __restrict__ b3,
                           const float* __restrict__ W4, const float* __restrict__ b4,
                           const float* __restrict__ W5, const float* __restrict__ b5,
                           const float* __restrict__ Wh, const float* __restrict__ bh,
                           const float* __restrict__ Wf, const float* __restrict__ bf,
                           v2f* __restrict__ ws) {
  const int i = blockIdx.x * blockDim.x + threadIdx.x;
  if (i >= NPAIR) return;
  float v;
  if      (i < OB1) v = W1[i - OW1];
  else if (i < OW2) v = b1[i - OB1];
  else if (i < OB2) v = W2[i - OW2];
  else if (i < OW3) v = b2[i - OB2];
  else if (i < OB3) v = W3[i - OW3];
  else if (i < OW4) v = b3[i - OB3];
  else if (i < OB4) v = W4[i - OW4];
  else if (i < OW5) v = b4[i - OB4];
  else if (i < OB5) v = W5[i - OW5];
  else if (i < OWH) v = b5[i - OB5];
  else if (i < OBH) v = Wh[i - OWH];
  else if (i < OWF) v = bh[i - OBH];
  else if (i < OBF) v = Wf[i - OWF];
  else              v = bf[i - OBF];
  v2f p; p.x = v; p.y = v;
  ws[i] = p;
}

__device__ __forceinline__ v2f splat(float v) {
  v2f r; r.x = v; r.y = v; return r;
}
__device__ __forceinline__ v2f vfma(v2f a, v2f b, v2f c) {
  return __builtin_elementwise_fma(a, b, c);
}
__device__ __forceinline__ float fexp(float x) {            // e^x
  return __builtin_amdgcn_exp2f(x * 1.4426950408889634f);
}

__device__ __forceinline__ v2f ftanh2(v2f x) {
  // tanh(x) = 1 - 2/(e^{2x}+1); inf-safe, no clamp needed.
  const v2f t = x * splat(2.8853900817779268f);  // 2*log2(e)
  v2f e;
  e.x = __builtin_amdgcn_exp2f(t.x);
  e.y = __builtin_amdgcn_exp2f(t.y);
  const v2f d = e + splat(1.0f);
  v2f r;
  r.x = __builtin_amdgcn_rcpf(d.x);
  r.y = __builtin_amdgcn_rcpf(d.y);
  return vfma(splat(-2.0f), r, splat(1.0f));
}

template <int F, int G, bool DOTANH>
__device__ __forceinline__ void dense(const v2f* __restrict__ Wd,
                                      const v2f* __restrict__ bd,
                                      const v2f (&in)[16], v2f (&out)[16]) {
#pragma unroll
  for (int j = 0; j < G; ++j) {
    v2f acc = bd[j];                      // uniform 8B -> s_load_dwordx2
#pragma unroll
    for (int i = 0; i < F; ++i)
      acc = vfma(in[i], Wd[j * F + i], acc);  // SGPR-pair weight operand
    out[j] = DOTANH ? ftanh2(acc) : acc;
  }
}

__global__ __launch_bounds__(TPB) void qcnn_fused(
    const float* __restrict__ x, const v2f* __restrict__ ws,
    const float* __restrict__ gammap, float* __restrict__ out, int n) {
  const int base = (blockIdx.x * TPB + threadIdx.x) * 2;  // contiguous pair
  const float g = gammap[0];

  v2f h0[16], hA[16], hB[16];

  // Two contiguous rows of x (8 floats each) -> 4 float4 loads, pack to v2f.
  if (base + 1 < n) {
    const float4* xp = reinterpret_cast<const float4*>(x) + (size_t)base * 2;
    float4 a0 = xp[0], a1 = xp[1];  // sample base
    float4 c0 = xp[2], c1 = xp[3];  // sample base+1
    h0[0].x = a0.x; h0[0].y = c0.x;
    h0[1].x = a0.y; h0[1].y = c0.y;
    h0[2].x = a0.z; h0[2].y = c0.z;
    h0[3].x = a0.w; h0[3].y = c0.w;
    h0[4].x = a1.x; h0[4].y = c1.x;
    h0[5].x = a1.y; h0[5].y = c1.y;
    h0[6].x = a1.z; h0[6].y = c1.z;
    h0[7].x = a1.w; h0[7].y = c1.w;
  } else if (base < n) {  // n odd tail (not hit for BATCH=2^21)
    const float4* xp = reinterpret_cast<const float4*>(x) + (size_t)base * 2;
    float4 a0 = xp[0], a1 = xp[1];
    h0[0] = splat(a0.x); h0[1] = splat(a0.y);
    h0[2] = splat(a0.z); h0[3] = splat(a0.w);
    h0[4] = splat(a1.x); h0[5] = splat(a1.y);
    h0[6] = splat(a1.z); h0[7] = splat(a1.w);
  } else {
#pragma unroll
    for (int i = 0; i < 8; ++i) h0[i] = splat(0.0f);
  }

  dense<8, 16, true>(ws + OW1, ws + OB1, h0, hA);
  dense<16, 16, true>(ws + OW2, ws + OB2, hA, hB);
  dense<16, 12, true>(ws + OW3, ws + OB3, hB, hA);
  dense<12, 8, true>(ws + OW4, ws + OB4, hA, hB);
  dense<8, 4, true>(ws + OW5, ws + OB5, hB, hA);
  dense<4, 4, false>(ws + OWH, ws + OBH, hA, hB);  // cls_out in hB[0..3]

  const v2f c0 = hB[0], c1 = hB[1], c2 = hB[2], c3 = hB[3];
  // qnn_out == 0 -> diff = cls_out; k = exp(-g * |cls|^2)
  const v2f ss = vfma(c0, c0, vfma(c1, c1, vfma(c2, c2, c3 * c3)));
  v2f k;
  k.x = fexp(-g * ss.x);
  k.y = fexp(-g * ss.y);
  // combined = [c0..c3, 0,0,0,0, k]; Wf is [2][9] row-major (paired in ws)
  const v2f* wf = ws + OWF;
  const v2f* bfp = ws + OBF;
  v2f o0 = bfp[0];
  o0 = vfma(wf[0], c0, o0);
  o0 = vfma(wf[1], c1, o0);
  o0 = vfma(wf[2], c2, o0);
  o0 = vfma(wf[3], c3, o0);
  o0 = vfma(wf[8], k, o0);
  v2f o1 = bfp[1];
  o1 = vfma(wf[9],  c0, o1);
  o1 = vfma(wf[10], c1, o1);
  o1 = vfma(wf[11], c2, o1);
  o1 = vfma(wf[12], c3, o1);
  o1 = vfma(wf[17], k, o1);
  // log_softmax over 2 classes, per sample
  const v2f m = __builtin_elementwise_max(o0, o1);
  const float s0 = fexp(o0.x - m.x) + fexp(o1.x - m.x);
  const float s1 = fexp(o0.y - m.y) + fexp(o1.y - m.y);
  const float lse0 = m.x + __builtin_amdgcn_logf(s0) * 0.6931471805599453f;
  const float lse1 = m.y + __builtin_amdgcn_logf(s1) * 0.6931471805599453f;

  if (base + 1 < n) {
    float4 r;
    r.x = o0.x - lse0;
    r.y = o1.x - lse0;
    r.z = o0.y - lse1;
    r.w = o1.y - lse1;
    reinterpret_cast<float4*>(out)[base / 2] = r;
  } else if (base < n) {
    float2 r;
    r.x = o0.x - lse0;
    r.y = o1.x - lse0;
    reinterpret_cast<float2*>(out)[base] = r;
  }
}

extern "C" void kernel_launch(void* const* d_in, const int* in_sizes, int n_in,
                              void* d_out, int out_size, void* d_ws, size_t ws_size,
                              hipStream_t stream) {
  const float* x  = (const float*)d_in[0];
  const float* W1 = (const float*)d_in[1];
  const float* b1 = (const float*)d_in[2];
  const float* W2 = (const float*)d_in[3];
  const float* b2 = (const float*)d_in[4];
  const float* W3 = (const float*)d_in[5];
  const float* b3 = (const float*)d_in[6];
  const float* W4 = (const float*)d_in[7];
  const float* b4 = (const float*)d_in[8];
  const float* W5 = (const float*)d_in[9];
  const float* b5 = (const float*)d_in[10];
  const float* Wh = (const float*)d_in[11];
  const float* bh = (const float*)d_in[12];
  const float* Wf = (const float*)d_in[13];
  const float* bf = (const float*)d_in[14];
  const float* gm = (const float*)d_in[15];

  v2f* ws = (v2f*)d_ws;

  prep_pairs<<<(NPAIR + TPB - 1) / TPB, TPB, 0, stream>>>(
      W1, b1, W2, b2, W3, b3, W4, b4, W5, b5, Wh, bh, Wf, bf, ws);

  const int n = in_sizes[0] / 8;  // BATCH
  const int grid = (n + TPB * 2 - 1) / (TPB * 2);
  qcnn_fused<<<grid, TPB, 0, stream>>>(x, ws, gm, (float*)d_out, n);
}